// Round 9
// baseline (32864.621 us; speedup 1.0000x reference)
//
#include <hip/hip_runtime.h>
#include <hip/hip_bf16.h>

// Problem constants
#define BB 128
#define TT 512
#define FF 256
#define CC 1024
#define KO 256

// Geometry: 512 blocks = 8 btiles (16 b-rows, XCD-local via bid&7) x 64
// ctiles (16 channels). 512 threads = 16 cl (channel, lane-minor) x 32 ks
// (K-split). Per-thread live set ~80 regs -> fits the 128-VGPR tier that
// 2 blocks/CU (4 waves/SIMD) imposes; R6/R8 spilled because 16-way K-split
// needed ~160 live at the same 128 cap.
#define NBLK 512
#define NTHR 512

__device__ __forceinline__ float tanh_fast(float v) {
  // tanh(v) = 1 - 2/(e^{2v}+1); exact at +-inf, ~1e-7 error elsewhere.
  const float e = __expf(2.f * v);
  return 1.f - 2.f / (e + 1.f);
}

// ---------------------------------------------------------------------------
// Group barrier: the 64 blocks sharing one btile (all on one XCD if dispatch
// is round-robin; correctness does not depend on that). Slot per (btile, t),
// counters zeroed each launch -> no sense reversal. Counter lines are
// btile-private (cnt[btile*512 + t]) so atomics/polls stay XCD-local.
// ---------------------------------------------------------------------------
__device__ __forceinline__ void group_barrier(int* __restrict__ cnt, int idx) {
  __syncthreads();
  if (threadIdx.x == 0) {
    __threadfence();  // release: this block's h writes device-visible
    __hip_atomic_fetch_add(&cnt[idx], 1, __ATOMIC_ACQ_REL,
                           __HIP_MEMORY_SCOPE_AGENT);
    while (__hip_atomic_load(&cnt[idx], __ATOMIC_ACQUIRE,
                             __HIP_MEMORY_SCOPE_AGENT) < 64) {
      __builtin_amdgcn_s_sleep(1);
    }
    __threadfence();  // acquire: invalidate stale L1 before reading peers' h
  }
  __syncthreads();
}

// ---------------------------------------------------------------------------
// h_t = tanh(u_t * tanh(g_t));  u = x@Wu+bu, g = [x,h]@Wg+bg.
// (n/d/a_max are dead in the reference: never reassigned -> e_t cancels.)
// Runs [tstart, tend) steps; fallback path uses tend-tstart==1 (no barrier
// executed -> no co-residency requirement).
//
// Lane layout: lane bits 0-3 = cl, bits 4-5 = ks&3, wave = ks>>2.
//  - h/x loads: 16 cl-lanes share one address (free broadcast); each 64B
//    h-line is consumed by exactly one wave -> h tile read once per block.
//  - ks-reduction: shfl_xor(16|32) in-wave, then 16 KB LDS across waves.
// ---------------------------------------------------------------------------
__global__ __launch_bounds__(NTHR, 4) void rwa_steps(
    const float* __restrict__ x,   // [B][T][F]
    const float* __restrict__ Wg,  // [F+C][C]
    const float* __restrict__ bg,  // [C]
    const float* __restrict__ Wu,  // [F][C]
    const float* __restrict__ bu,  // [C]
    float* __restrict__ hbuf,      // ws: [2][B][C]
    int* __restrict__ cnt,         // ws: [8][512] barrier counters
    int tstart, int tend) {
  __shared__ float sg[2048];  // [wave][b][cl] g-partials
  __shared__ float su[2048];  // [wave][b][cl] u-partials

  const int tid = threadIdx.x;
  const int bid = blockIdx.x;
  const int btile = bid & 7;        // XCD-local group id
  const int b0 = btile * 16;        // batch tile origin
  const int c0 = (bid >> 3) * 16;   // channel tile origin
  const int cl = tid & 15;          // channel within tile (lane-minor)
  const int ks = tid >> 4;          // 0..31 K-slice
  const int c = c0 + cl;

  // ---- persistent weight registers (one-time, 64B-coalesced per cl-group).
  // wh[i]: Wg h-rows 256+4*(ks+32i)+j, col c. 48 floats/thread total.
  float4 wh[8];
#pragma unroll
  for (int i = 0; i < 8; ++i) {
    const int k = FF + 4 * (ks + 32 * i);
    wh[i].x = Wg[(size_t)(k + 0) * CC + c];
    wh[i].y = Wg[(size_t)(k + 1) * CC + c];
    wh[i].z = Wg[(size_t)(k + 2) * CC + c];
    wh[i].w = Wg[(size_t)(k + 3) * CC + c];
  }
  float4 wgx[2], wux[2];
#pragma unroll
  for (int i = 0; i < 2; ++i) {
    const int k = 4 * (ks + 32 * i);
    wgx[i].x = Wg[(size_t)(k + 0) * CC + c];
    wgx[i].y = Wg[(size_t)(k + 1) * CC + c];
    wgx[i].z = Wg[(size_t)(k + 2) * CC + c];
    wgx[i].w = Wg[(size_t)(k + 3) * CC + c];
    wux[i].x = Wu[(size_t)(k + 0) * CC + c];
    wux[i].y = Wu[(size_t)(k + 1) * CC + c];
    wux[i].z = Wu[(size_t)(k + 2) * CC + c];
    wux[i].w = Wu[(size_t)(k + 3) * CC + c];
  }
  const float bgv = bg[c];
  const float buv = bu[c];

  for (int t = tstart; t < tend; ++t) {
    const float* __restrict__ hp = hbuf + (size_t)(t & 1) * (BB * CC);
    float* __restrict__ hn = hbuf + (size_t)((t + 1) & 1) * (BB * CC);
    const float* __restrict__ hb = hp + (size_t)b0 * CC;
    const float* __restrict__ xb = x + (size_t)b0 * TT * FF + (size_t)t * FF;

    float accg[16], accu[16];
#pragma unroll
    for (int b = 0; b < 16; ++b) {
      accg[b] = 0.f;
      accu[b] = 0.f;
    }

    // ---- x-part (K=256)
#pragma unroll
    for (int i = 0; i < 2; ++i) {
      const int f = 4 * (ks + 32 * i);
#pragma unroll
      for (int b = 0; b < 16; ++b) {
        const float4 xq = *(const float4*)(xb + (size_t)b * TT * FF + f);
        accg[b] = fmaf(wgx[i].x, xq.x, accg[b]);
        accg[b] = fmaf(wgx[i].y, xq.y, accg[b]);
        accg[b] = fmaf(wgx[i].z, xq.z, accg[b]);
        accg[b] = fmaf(wgx[i].w, xq.w, accg[b]);
        accu[b] = fmaf(wux[i].x, xq.x, accu[b]);
        accu[b] = fmaf(wux[i].y, xq.y, accu[b]);
        accu[b] = fmaf(wux[i].z, xq.z, accu[b]);
        accu[b] = fmaf(wux[i].w, xq.w, accu[b]);
      }
    }

    // ---- h-part (K=1024): weights from regs, h quads from L2 (once/block)
#pragma unroll
    for (int i = 0; i < 8; ++i) {
      const int k = 4 * (ks + 32 * i);
#pragma unroll
      for (int b = 0; b < 16; ++b) {
        const float4 hq = *(const float4*)(hb + (size_t)b * CC + k);
        accg[b] = fmaf(wh[i].x, hq.x, accg[b]);
        accg[b] = fmaf(wh[i].y, hq.y, accg[b]);
        accg[b] = fmaf(wh[i].z, hq.z, accg[b]);
        accg[b] = fmaf(wh[i].w, hq.w, accg[b]);
      }
    }

    // ---- in-wave reduce over the 4 same-wave ks slices (lane bits 4,5)
#pragma unroll
    for (int b = 0; b < 16; ++b) {
      accg[b] += __shfl_xor(accg[b], 16);
      accg[b] += __shfl_xor(accg[b], 32);
      accu[b] += __shfl_xor(accu[b], 16);
      accu[b] += __shfl_xor(accu[b], 32);
    }

    // ---- cross-wave reduce via LDS: one lane-group per wave writes
    if ((ks & 3) == 0) {
      const int w = ks >> 2;
      float* sgw = sg + w * 256 + cl;
      float* suw = su + w * 256 + cl;
#pragma unroll
      for (int b = 0; b < 16; ++b) {
        sgw[b * 16] = accg[b];
        suw[b * 16] = accu[b];
      }
    }
    __syncthreads();

    if (tid < 256) {
      const int fb = tid >> 4;  // batch row within tile
      const int fc = tid & 15;  // channel within tile (== cl)
      float gs = 0.f, us = 0.f;
#pragma unroll
      for (int w = 0; w < 8; ++w) {
        gs += sg[w * 256 + fb * 16 + fc];
        us += su[w * 256 + fb * 16 + fc];
      }
      const float gv = gs + bgv;
      const float uv = us + buv;
      // n/d/a_max dead: n_t/d_t == z_t exactly -> h = tanh(u*tanh(g))
      hn[(size_t)(b0 + fb) * CC + (c0 + fc)] = tanh_fast(uv * tanh_fast(gv));
    }

    if (t + 1 < tend) group_barrier(cnt, btile * 512 + t);
  }
}

// ---- init: copy h0 -> hbuf[0] (256*512 == B*C exactly)
__global__ void rwa_init(const float* __restrict__ h0,
                         float* __restrict__ hbuf) {
  const int idx = blockIdx.x * 512 + threadIdx.x;
  hbuf[idx] = h0[idx];
}

// ---- epilogue: out = h_T @ Wo + bo (h_T = hbuf[0], TT even)
__global__ __launch_bounds__(512) void rwa_out(const float* __restrict__ hT,
                                               const float* __restrict__ Wo,
                                               const float* __restrict__ bo,
                                               float* __restrict__ out) {
  __shared__ float red[512];
  const int bid = blockIdx.x;  // 256 blocks: (b, half of K-outputs)
  const int b = bid >> 1;
  const int ko0 = (bid & 1) * 128;
  const int o = threadIdx.x & 127;
  const int kslice = threadIdx.x >> 7;  // 0..3, 4-way K split
  const float* __restrict__ hr = hT + (size_t)b * CC + kslice * 256;
  const float* __restrict__ wr = Wo + (size_t)(kslice * 256) * KO + ko0 + o;
  float acc = 0.f;
#pragma unroll 8
  for (int j = 0; j < 256; ++j) acc = fmaf(hr[j], wr[(size_t)j * KO], acc);
  red[threadIdx.x] = acc;
  __syncthreads();
  if (threadIdx.x < 128) {
    out[(size_t)b * KO + ko0 + threadIdx.x] =
        (red[threadIdx.x] + red[128 + threadIdx.x]) +
        (red[256 + threadIdx.x] + red[384 + threadIdx.x]) +
        bo[ko0 + threadIdx.x];
  }
}

// ---------------------------------------------------------------------------
// Inputs (setup_inputs order): 0:x 1:n 2:d 3:h 4:a_max 5:Wg 6:bg 7:Wu 8:bu
// 9:Wa 10:Wo 11:bo.  n/d/a_max/Wa provably unused (dead state, see header).
// Coop launch preferred (co-residency: 512 blocks = 2/CU x 256 CU, 16 KB LDS,
// 128-VGPR cap via __launch_bounds__(512,4)); on ANY coop error, fall back to
// 512 single-step launches (stream-ordered, no barriers executed).
// ---------------------------------------------------------------------------
extern "C" void kernel_launch(void* const* d_in, const int* in_sizes, int n_in,
                              void* d_out, int out_size, void* d_ws,
                              size_t ws_size, hipStream_t stream) {
  const float* x = (const float*)d_in[0];
  const float* h0 = (const float*)d_in[3];
  const float* Wg = (const float*)d_in[5];
  const float* bg = (const float*)d_in[6];
  const float* Wu = (const float*)d_in[7];
  const float* bu = (const float*)d_in[8];
  const float* Wo = (const float*)d_in[10];
  const float* bo = (const float*)d_in[11];
  float* out = (float*)d_out;

  float* hbuf = (float*)d_ws;  // [2][B][C] = 1 MiB
  int* cnt = (int*)((char*)d_ws + (size_t)2 * BB * CC * sizeof(float));

  hipMemsetAsync(cnt, 0, (size_t)8 * 512 * sizeof(int), stream);
  rwa_init<<<dim3(256), dim3(512), 0, stream>>>(h0, hbuf);

  int t0 = 0, t1 = TT;
  void* args[] = {(void*)&x,  (void*)&Wg,   (void*)&bg,  (void*)&Wu,
                  (void*)&bu, (void*)&hbuf, (void*)&cnt, (void*)&t0,
                  (void*)&t1};
  hipError_t e = hipLaunchCooperativeKernel((void*)rwa_steps, dim3(NBLK),
                                            dim3(NTHR), args, 0, stream);
  if (e != hipSuccess) {
    (void)hipGetLastError();  // clear sticky error
    for (int t = 0; t < TT; ++t) {
      hipLaunchKernelGGL(rwa_steps, dim3(NBLK), dim3(NTHR), 0, stream, x, Wg,
                         bg, Wu, bu, hbuf, cnt, t, t + 1);
    }
  }

  rwa_out<<<dim3(256), dim3(512), 0, stream>>>(hbuf, Wo, bo, out);
}